// Round 8
// baseline (822.445 us; speedup 1.0000x reference)
//
#include <hip/hip_runtime.h>
#include <hip/hip_fp16.h>
#include <math.h>

#define NJETS 65536

typedef __attribute__((ext_vector_type(8))) short short8;
typedef __attribute__((ext_vector_type(4))) float f32x4;

__device__ __forceinline__ float bf2f(unsigned short u){
  union { unsigned int i; float f; } v; v.i = ((unsigned int)u) << 16; return v.f;
}
__device__ __forceinline__ unsigned short f2bf(float f){
  union { float ff; unsigned int i; } v; v.ff = f;
  unsigned int r = (v.i + 0x7fffu + ((v.i >> 16) & 1u)) >> 16;   // RTNE
  return (unsigned short)r;
}
__device__ __forceinline__ float silu_f(float t){
  return t * __builtin_amdgcn_rcpf(1.f + __expf(-t));
}

// Truncation split of two fp32 into packed bf16 hi-pair and bf16 lo-pair,
// using v_perm_b32 for the 16-bit packing (1 instr per pack).
// hi+lo captures 17 mantissa bits (error <= 2^-17 |x|).
__device__ __forceinline__ void split2(float x0, float x1, unsigned &hi, unsigned &lo){
  union { float f; unsigned u; } a0, a1, m0, m1, r0, r1;
  a0.f = x0; a1.f = x1;
  m0.u = a0.u & 0xffff0000u;
  m1.u = a1.u & 0xffff0000u;
  r0.f = x0 - m0.f;
  r1.f = x1 - m1.f;
  hi = __builtin_amdgcn_perm(a1.u, a0.u, 0x07060302u);  // {a1.hi16, a0.hi16}
  lo = __builtin_amdgcn_perm(r1.u, r0.u, 0x07060302u);  // {r1.hi16, r0.hi16}
}

// Fragment-major weight prep: frag[((kk*T + tile)*64 + lane)*8 + e]
//   = W[tile*16 + (lane&15)][kk*32 + (lane>>4)*8 + e]   (0 outside valid range)
__global__ void prep_w(const float* __restrict__ wie, const float* __restrict__ wec,
                       const float* __restrict__ wbi, const float* __restrict__ wbo,
                       const float* __restrict__ wdc, const float* __restrict__ wor,
                       unsigned short* pieh, unsigned short* piel,
                       unsigned short* pech, unsigned short* pecl,
                       unsigned short* pbih, unsigned short* pbil,
                       unsigned short* pboh, unsigned short* pbol,
                       unsigned short* pdch, unsigned short* pdcl,
                       unsigned short* porh, unsigned short* porl)
{
  int t = blockIdx.x*256 + threadIdx.x;   // 0..16383
  int e = t & 7, l = (t >> 3) & 63, rem = t >> 9;
  int r16 = l & 15;
  int kq = (l >> 4)*8 + e;                // k within one 32-block
  #define WSPLIT(val, H, L) { float w_=(val); unsigned short h_=f2bf(w_); H[t]=h_; L[t]=f2bf(w_-bf2f(h_)); }
  if (t < 4096){                          // KK=1, T=8 (ie: K=3 pad, bo: K=16 pad)
    int tile = rem & 7; int row = tile*16 + r16; int k = kq;
    WSPLIT((k < 3) ? wie[row*3 + k] : 0.f, pieh, piel);
    WSPLIT((k < 16) ? wbo[row*16 + k] : 0.f, pboh, pbol);
  }
  if (t < 16384){                         // KK=4, T=8 (ec, dc)
    int kk = rem >> 3, tile = rem & 7; int row = tile*16 + r16; int k = kk*32 + kq;
    WSPLIT(wec[row*128 + k], pech, pecl);
    WSPLIT(wdc[row*128 + k], pdch, pdcl);
  }
  if (t < 2048){                          // KK=4, T=1 (bi: 16 rows; or: 3 rows pad)
    int kk = rem; int row = r16; int k = kk*32 + kq;
    WSPLIT(wbi[row*128 + k], pbih, pbil);
    WSPLIT((row < 3) ? wor[row*128 + k] : 0.f, porh, porl);
  }
  #undef WSPLIT
}

// Exact input-side outputs: out0 = jPxPyPzE, out2 = j_rot (copy)
__global__ void k_out02(const float* __restrict__ jin, float* __restrict__ out0,
                        float* __restrict__ out2)
{
  int b = blockIdx.x*256 + threadIdx.x;
  if (b >= NJETS) return;
  #pragma unroll
  for (int p=0;p<4;p++){
    float ptv = jin[b*16+p], ev = jin[b*16+4+p], ph = jin[b*16+8+p], mv = jin[b*16+12+p];
    out0[(size_t)b*16 + p]      = ptv*cosf(ph);
    out0[(size_t)b*16 + 4 + p]  = ptv*sinf(ph);
    out0[(size_t)b*16 + 8 + p]  = ptv*sinhf(ev);
    float tt = ptv*coshf(ev);
    out0[(size_t)b*16 + 12 + p] = sqrtf(tt*tt + mv*mv);
  }
  #pragma unroll
  for (int i=0;i<16;i+=4)
    *(float4*)(out2 + (size_t)b*16 + i) = *(const float4*)(jin + (size_t)b*16 + i);
}

// Fused conv kernel, one chunk of whole GBN groups. M=256 rows/block, 8 waves,
// 2 row-stripes/wave (stripe1 = +128). Hi-weights staged in LDS fragment-major; lo from L2.
// Epilogue for OTILES==8 stages packed fp16 rows in per-wave LDS tiles, then
// stores 1KB fully-coalesced per instruction.
// Preamble (PREVC>0): per-block reduce of previous layer's partials -> alpha/beta in LDS.
// SRC: 0 = jp from j; 1 = fp16 y[128] + affsilu; 3 = fp32 y3[16] + affsilu + z write.
// OTILES==8 -> fp16 output; OTILES==1 -> fp32 output (16-ch).
template<int OTILES, int KK, int SRC, int AUXOUT, int AUXIN, int PREVC>
__global__ __launch_bounds__(512, 6)
void conv_k(const float* __restrict__ jin, int rowbase,
            const void* __restrict__ yin,
            const float* __restrict__ partIn,
            const float* __restrict__ prevGain, const float* __restrict__ prevBias,
            int prevCvalid,
            const unsigned short* __restrict__ whM, const unsigned short* __restrict__ wlM,
            const unsigned short* __restrict__ whA, const unsigned short* __restrict__ wlA,
            const float* __restrict__ bias, int cvalid,
            void* __restrict__ yout, float* __restrict__ youtaux,
            const float* __restrict__ yinaux,
            float* __restrict__ partOut, float* __restrict__ zout)
{
  constexpr int COUT = OTILES*16;
  constexpr int WHBYTES = KK*OTILES*512*2;
  constexpr int STBYTES = (OTILES==8) ? 8*16*68*4 : 0;   // 8 waves x [16][68] dwords
  constexpr int UBYTES  = (WHBYTES > STBYTES) ? WHBYTES : STBYTES;
  const int tid = threadIdx.x;
  const int wv = tid >> 6, lane = tid & 63, r16 = lane & 15, g4 = lane >> 4;
  const int blk = blockIdx.x;
  const int row0 = blk*256 + wv*16;     // stripe0 rows (chunk-local); stripe1 = +128
  const int grp = blk >> 4;             // 16 blocks per GBN group

  __shared__ __align__(16) char ldsU[UBYTES];            // weights | store-staging (union)
  unsigned short* ldsWh = (unsigned short*)ldsU;
  __shared__ __align__(16) unsigned short ldsWhA[AUXOUT ? KK*512 : 8];
  __shared__ float sAB[256];
  __shared__ float sc[8][OTILES][16][2];

  // ---- preamble: compute this group's alpha/beta from partIn ----
  if (PREVC > 0){
    constexpr int NENT = PREVC*2;
    if (tid < NENT){
      float s = 0.f;
      const float* p = partIn + (size_t)(grp*16)*256 + tid;
      #pragma unroll
      for (int i=0;i<16;i++) s += p[(size_t)i*256];
      float other = __shfl_xor(s, 1);
      if ((tid & 1) == 0){
        int c = tid >> 1;
        float mean = s * (1.f/4096.f);
        float var  = other * (1.f/4096.f) - mean*mean;
        float a = 0.f, b = 0.f;
        if (c < prevCvalid){
          a = prevGain[c] * rsqrtf(var + 1e-5f);
          b = prevBias[c] - mean*a;
        }
        sAB[c] = a; sAB[128 + c] = b;
      }
    }
  }
  { // stage hi-weights into LDS (fragment-major is linear -> coalesced)
    const float4* gw = (const float4*)whM;
    float4* lw = (float4*)ldsU;
    for (int i = tid; i < KK*OTILES*64; i += 512) lw[i] = gw[i];
    if (AUXOUT){
      const float4* ga = (const float4*)whA;
      float4* la = (float4*)ldsWhA;
      for (int i = tid; i < KK*64; i += 512) la[i] = ga[i];
    }
  }
  __syncthreads();

  f32x4 acc[2][OTILES];
  f32x4 accA[2];
  #pragma unroll
  for (int s=0;s<2;s++){
    #pragma unroll
    for (int t=0;t<OTILES;t++){
      int c = t*16 + r16;
      float bv = (c < cvalid) ? bias[c] : 0.f;
      if (AUXIN){
        #pragma unroll
        for (int jj=0;jj<4;jj++)
          acc[s][t][jj] = bv + yinaux[(size_t)(row0 + s*128 + g4*4 + jj)*16 + r16];
      } else {
        acc[s][t][0]=bv; acc[s][t][1]=bv; acc[s][t][2]=bv; acc[s][t][3]=bv;
      }
    }
    if (AUXOUT){ accA[s][0]=0.f; accA[s][1]=0.f; accA[s][2]=0.f; accA[s][3]=0.f; }
  }

  auto loadA = [&](int kk, int s, float* xs){
    const int rowL = row0 + s*128 + r16;
    if (SRC == 1){
      const unsigned short* yb = (const unsigned short*)yin;
      union { uint4 u; unsigned short us[8]; } raw;
      raw.u = *(const uint4*)(yb + (size_t)rowL*128 + kk*32 + g4*8);
      #pragma unroll
      for (int e=0;e<8;e++) xs[e] = __half2float(__ushort_as_half(raw.us[e]));
    } else if (SRC == 3){
      const float* yf = (const float*)yin;
      if (g4 < 2){
        *(float4*)&xs[0] = *(const float4*)(yf + (size_t)rowL*16 + g4*8);
        *(float4*)&xs[4] = *(const float4*)(yf + (size_t)rowL*16 + g4*8 + 4);
      } else {
        #pragma unroll
        for (int e=0;e<8;e++) xs[e] = 0.f;
      }
    } else { // SRC == 0
      #pragma unroll
      for (int e=0;e<8;e++) xs[e] = 0.f;
      if (g4 == 0){
        int rowG = rowbase + rowL; int b = rowG >> 2, p = rowG & 3;
        xs[0] = jin[b*16 + p];
        xs[1] = jin[b*16 + 4 + p];
        xs[2] = jin[b*16 + 8 + p];
      }
    }
  };

  float cur[2][8], nxt[2][8];
  loadA(0, 0, cur[0]); loadA(0, 1, cur[1]);

  #pragma unroll
  for (int kk=0; kk<KK; kk++){
    if (kk+1 < KK){ loadA(kk+1, 0, nxt[0]); loadA(kk+1, 1, nxt[1]); }

    float alf[8], bef[8];
    if (SRC != 0){
      const int kb = (SRC==1) ? (kk*32 + g4*8) : (g4 < 2 ? g4*8 : 0);
      #pragma unroll
      for (int e=0;e<8;e++){ alf[e] = sAB[kb+e]; bef[e] = sAB[128+kb+e]; }
    }

    short8 ah[2], al[2];
    #pragma unroll
    for (int s=0;s<2;s++){
      float xs[8];
      if (SRC == 0){
        #pragma unroll
        for (int e=0;e<8;e++) xs[e] = cur[s][e];
        if (g4 == 0) xs[0] = log1pf(cur[s][0]);
      } else if (SRC == 1){
        #pragma unroll
        for (int e=0;e<8;e++) xs[e] = silu_f(fmaf(cur[s][e], alf[e], bef[e]));
      } else { // SRC == 3
        if (g4 < 2){
          const int kb = g4*8;
          const int rowG = rowbase + row0 + s*128 + r16;
          const int b = rowG >> 2, p = rowG & 3;
          #pragma unroll
          for (int e=0;e<8;e++){
            float sv = silu_f(fmaf(cur[s][e], alf[e], bef[e]));
            zout[(size_t)b*64 + (size_t)(kb+e)*4 + p] = sv;   // z (B,16,4)
            xs[e] = sv;
          }
        } else {
          #pragma unroll
          for (int e=0;e<8;e++) xs[e] = 0.f;
        }
      }
      union { uint4 u; short8 v; } AH, AL;
      #pragma unroll
      for (int e=0;e<8;e+=2){
        unsigned hi, lo;
        split2(xs[e], xs[e+1], hi, lo);
        ((unsigned*)&AH)[e>>1] = hi;
        ((unsigned*)&AL)[e>>1] = lo;
      }
      ah[s] = AH.v; al[s] = AL.v;
    }

    #pragma unroll
    for (int t=0;t<OTILES;t++){
      const int off = ((kk*OTILES + t)*64 + lane)*8;
      short8 Bh = *(const short8*)(ldsWh + off);
      union { uint4 u; short8 v; } Bl; Bl.u = *(const uint4*)(wlM + off);
      #pragma unroll
      for (int s=0;s<2;s++){
        acc[s][t] = __builtin_amdgcn_mfma_f32_16x16x32_bf16(ah[s], Bh,   acc[s][t], 0,0,0);
        acc[s][t] = __builtin_amdgcn_mfma_f32_16x16x32_bf16(al[s], Bh,   acc[s][t], 0,0,0);
        acc[s][t] = __builtin_amdgcn_mfma_f32_16x16x32_bf16(ah[s], Bl.v, acc[s][t], 0,0,0);
      }
    }
    if (AUXOUT){
      const int off = (kk*64 + lane)*8;
      short8 Bh = *(const short8*)(ldsWhA + off);
      union { uint4 u; short8 v; } Bl; Bl.u = *(const uint4*)(wlA + off);
      #pragma unroll
      for (int s=0;s<2;s++){
        accA[s] = __builtin_amdgcn_mfma_f32_16x16x32_bf16(ah[s], Bh,   accA[s], 0,0,0);
        accA[s] = __builtin_amdgcn_mfma_f32_16x16x32_bf16(al[s], Bh,   accA[s], 0,0,0);
        accA[s] = __builtin_amdgcn_mfma_f32_16x16x32_bf16(ah[s], Bl.v, accA[s], 0,0,0);
      }
    }

    #pragma unroll
    for (int s=0;s<2;s++)
      #pragma unroll
      for (int e=0;e<8;e++) cur[s][e] = nxt[s][e];
  }

  // ---- epilogue part 1: per-channel sums (+ direct store for 16-ch fp32 out) ----
  #pragma unroll
  for (int t=0;t<OTILES;t++){
    float ss1 = 0.f, ss2 = 0.f;
    const int c = t*16 + r16;
    #pragma unroll
    for (int s=0;s<2;s++){
      #pragma unroll
      for (int jj=0;jj<4;jj++){
        float v = acc[s][t][jj];
        if (OTILES == 1)
          ((float*)yout)[(size_t)(row0 + s*128 + g4*4 + jj)*16 + c] = v;
        ss1 += v; ss2 += v*v;
      }
    }
    ss1 += __shfl_xor(ss1, 16); ss1 += __shfl_xor(ss1, 32);
    ss2 += __shfl_xor(ss2, 16); ss2 += __shfl_xor(ss2, 32);
    if (g4 == 0){ sc[wv][t][r16][0] = ss1; sc[wv][t][r16][1] = ss2; }
  }
  if (AUXOUT){
    #pragma unroll
    for (int s=0;s<2;s++)
      #pragma unroll
      for (int jj=0;jj<4;jj++)
        youtaux[(size_t)(row0 + s*128 + g4*4 + jj)*16 + r16] = accA[s][jj];
  }
  __syncthreads();   // all waves done with ldsWh (staging aliases it) and sc filled

  // ---- epilogue part 2: fp16 y store via per-wave LDS transpose (1KB/instr) ----
  if (OTILES == 8){
    unsigned* stg = (unsigned*)ldsU + wv*(16*68);
    #pragma unroll
    for (int s=0;s<2;s++){
      #pragma unroll
      for (int t=0;t<8;t++){
        #pragma unroll
        for (int jj=0;jj<4;jj++){
          unsigned u = (unsigned)__half_as_ushort(__float2half_rn(acc[s][t][jj]));
          unsigned partner = __shfl_xor((int)u, 1);
          if ((r16 & 1) == 0)
            stg[(g4*4+jj)*68 + t*8 + (r16>>1)] = u | (partner << 16);
        }
      }
      #pragma unroll
      for (int i=0;i<4;i++){
        const int r = i*4 + g4;
        const int d0 = r16*4;
        uint4 val = *(const uint4*)(stg + r*68 + d0);
        *(uint4*)((unsigned*)yout + (size_t)(row0 + s*128 + r)*64 + d0) = val;
      }
    }
  }
  if (tid < COUT*2){
    int c = tid >> 1, sbit = tid & 1;
    float p = 0.f;
    #pragma unroll
    for (int w=0;w<8;w++) p += sc[w][c>>4][c&15][sbit];
    partOut[(size_t)blk*256 + tid] = p;
  }
}

// Output-side: compute ab6 from L6 partials, then affsilu(y6) -> out3 / out1.
__global__ void k_out13(const float* __restrict__ y6, const float* __restrict__ partIn,
                        const float* __restrict__ gor, const float* __restrict__ beor,
                        int jetbase, int njets_chunk,
                        float* __restrict__ out1, float* __restrict__ out3)
{
  __shared__ float sA[3], sB[3];
  int g = blockIdx.x >> 2;                 // 4 blocks (256 jets) per group
  if (threadIdx.x < 6){
    int tidp = threadIdx.x;
    float s = 0.f;
    const float* p = partIn + (size_t)(g*16)*256 + tidp;
    #pragma unroll
    for (int i=0;i<16;i++) s += p[(size_t)i*256];
    float other = __shfl_xor(s, 1);
    if ((tidp & 1) == 0){
      int c = tidp >> 1;
      float mean = s * (1.f/4096.f);
      float var  = other * (1.f/4096.f) - mean*mean;
      float a = gor[c] * rsqrtf(var + 1e-5f);
      sA[c] = a; sB[c] = beor[c] - mean*a;
    }
  }
  __syncthreads();
  int jl = blockIdx.x*256 + threadIdx.x;
  if (jl >= njets_chunk) return;
  int b = jetbase + jl;
  float a0 = sA[0], a1 = sA[1], a2 = sA[2];
  float b0 = sB[0], b1 = sB[1], b2 = sB[2];
  #pragma unroll
  for (int p=0;p<4;p++){
    size_t row = (size_t)jl*4 + p;
    float x0 = silu_f(fmaf(y6[row*16+0], a0, b0));
    float x1 = silu_f(fmaf(y6[row*16+1], a1, b1));
    float x2 = silu_f(fmaf(y6[row*16+2], a2, b2));
    float rPt = coshf(x0) + 39.f;
    out3[(size_t)b*12 + p]     = rPt;
    out3[(size_t)b*12 + 4 + p] = x1;
    out3[(size_t)b*12 + 8 + p] = x2;
    float rPz = rPt * sinhf(x1);
    out1[(size_t)b*16 + p]      = rPt * cosf(x2);
    out1[(size_t)b*16 + 4 + p]  = rPt * sinf(x2);
    out1[(size_t)b*16 + 8 + p]  = rPz;
    out1[(size_t)b*16 + 12 + p] = sqrtf(rPt*rPt + rPz*rPz);
  }
}

extern "C" void kernel_launch(void* const* d_in, const int* in_sizes, int n_in,
                              void* d_out, int out_size, void* d_ws, size_t ws_size,
                              hipStream_t stream)
{
  const float* j    = (const float*)d_in[0];
  const float* w_ie = (const float*)d_in[1];
  const float* b_ie = (const float*)d_in[2];
  const float* g_ie = (const float*)d_in[3];
  const float* be_ie= (const float*)d_in[4];
  const float* w_ec = (const float*)d_in[5];
  const float* b_ec = (const float*)d_in[6];
  const float* g_ec = (const float*)d_in[7];
  const float* be_ec= (const float*)d_in[8];
  const float* w_bi = (const float*)d_in[9];
  const float* b_bi = (const float*)d_in[10];
  const float* g_bi = (const float*)d_in[11];
  const float* be_bi= (const float*)d_in[12];
  const float* w_bo = (const float*)d_in[13];
  const float* b_bo = (const float*)d_in[14];
  const float* g_bo = (const float*)d_in[15];
  const float* be_bo= (const float*)d_in[16];
  const float* w_dc = (const float*)d_in[17];
  const float* b_dc = (const float*)d_in[18];
  const float* w_or = (const float*)d_in[19];
  const float* b_or = (const float*)d_in[20];
  const float* g_or = (const float*)d_in[21];
  const float* be_or= (const float*)d_in[22];

  float* out  = (float*)d_out;
  float* out0 = out;
  float* out1 = out + 1048576;
  float* out2 = out + 2097152;
  float* out3 = out + 3145728;
  float* out4 = out + 3932160;   // z (B,16,4)

  char* ws = (char*)d_ws;
  unsigned short* pieh = (unsigned short*)(ws);
  unsigned short* piel = pieh + 4096;
  unsigned short* pech = piel + 4096;
  unsigned short* pecl = pech + 16384;
  unsigned short* pbih = pecl + 16384;
  unsigned short* pbil = pbih + 2048;
  unsigned short* pboh = pbil + 2048;
  unsigned short* pbol = pboh + 4096;
  unsigned short* pdch = pbol + 4096;
  unsigned short* pdcl = pdch + 16384;
  unsigned short* porh = pdcl + 16384;
  unsigned short* porl = porh + 2048;

  // Chunking: G whole GBN groups (1024 jets = 4096 rows) per chunk.
  // perG = yA + yB (fp16 [4096][128]) + y3 (fp32 [4096][16]) + 2 part bufs
  const size_t fixedB = 196608;
  const size_t perG   = 2424832;   // superset of 2*1048576 + 262144 + 2*16384
  int G = 64;
  while (G > 1 && fixedB + (size_t)G*perG > ws_size) G >>= 1;

  unsigned short* yA = (unsigned short*)(ws + fixedB);   // fp16 [G*4096][128]
  unsigned short* yB = yA + (size_t)G*4096*128;          // fp16 [G*4096][128]
  float* y3    = (float*)(yB + (size_t)G*4096*128);      // fp32 [G*4096][16]
  float* partA = y3 + (size_t)G*4096*16;                 // [G*16][256]
  float* partB = partA + (size_t)G*16*256;               // [G*16][256]

  prep_w<<<64,256,0,stream>>>(w_ie,w_ec,w_bi,w_bo,w_dc,w_or,
                              pieh,piel,pech,pecl,pbih,pbil,pboh,pbol,pdch,pdcl,porh,porl);
  k_out02<<<256,256,0,stream>>>(j, out0, out2);

  for (int g0 = 0; g0 < 64; g0 += G){
    const int R0 = g0*4096;
    const int JB = g0*1024;
    const int NB = G*16;             // blocks per conv (256 rows each)
    // L1: jp -> y1 (yA fp16); partials -> partA
    conv_k<8,1,0,0,0,0><<<NB,512,0,stream>>>(j, R0, nullptr,
        nullptr, nullptr, nullptr, 0,
        pieh, piel, nullptr, nullptr,
        b_ie, 128, yA, nullptr, nullptr, partA, nullptr);
    // L2: ab1 from partA (g_ie); y2 = Wec x1 (yB); y3a = Wbi x1 (y3); partials -> partB
    conv_k<8,4,1,1,0,128><<<NB,512,0,stream>>>(nullptr, R0, yA,
        partA, g_ie, be_ie, 128,
        pech, pecl, pbih, pbil,
        b_ec, 128, yB, y3, nullptr, partB, nullptr);
    // L3: ab2 from partB (g_ec); y3 = y3a + Wbi affsilu2(y2); partials -> partA
    conv_k<1,4,1,0,1,128><<<NB,512,0,stream>>>(nullptr, R0, yB,
        partB, g_ec, be_ec, 128,
        pbih, pbil, nullptr, nullptr,
        b_bi, 16, y3, nullptr, y3, partA, nullptr);
    // L4: ab3 from partA (g_bi); z = affsilu3(y3) -> out4; y4 = Wbo z (yA); partials -> partB
    conv_k<8,1,3,0,0,16><<<NB,512,0,stream>>>(nullptr, R0, y3,
        partA, g_bi, be_bi, 16,
        pboh, pbol, nullptr, nullptr,
        b_bo, 128, yA, nullptr, nullptr, partB, out4);
    // L5: ab4 from partB (g_bo); y5 = Wdc x4 (yB); y6a = Wor x4 (y3); partials -> partA
    conv_k<8,4,1,1,0,128><<<NB,512,0,stream>>>(nullptr, R0, yA,
        partB, g_bo, be_bo, 128,
        pdch, pdcl, porh, porl,
        b_dc, 128, yB, y3, nullptr, partA, nullptr);
    // L6: ab5 from partA (g_ec — reference reuses g_ec/be_ec); y6 = y6a + Wor affsilu5(y5); partials -> partB
    conv_k<1,4,1,0,1,128><<<NB,512,0,stream>>>(nullptr, R0, yB,
        partA, g_ec, be_ec, 128,
        porh, porl, nullptr, nullptr,
        b_or, 3, y3, nullptr, y3, partB, nullptr);
    // outputs 1 and 3 (ab6 from partB, g_or)
    k_out13<<<G*4,256,0,stream>>>(y3, partB, g_or, be_or, JB, G*1024, out1, out3);
  }
}

// Round 9
// 245.465 us; speedup vs baseline: 3.3506x; 3.3506x over previous
//
#include <hip/hip_runtime.h>
#include <hip/hip_fp16.h>
#include <math.h>

#define NJETS 65536

typedef __attribute__((ext_vector_type(8))) short short8;
typedef __attribute__((ext_vector_type(4))) float f32x4;

__device__ __forceinline__ float bf2f(unsigned short u){
  union { unsigned int i; float f; } v; v.i = ((unsigned int)u) << 16; return v.f;
}
__device__ __forceinline__ unsigned short f2bf(float f){
  union { float ff; unsigned int i; } v; v.ff = f;
  unsigned int r = (v.i + 0x7fffu + ((v.i >> 16) & 1u)) >> 16;   // RTNE
  return (unsigned short)r;
}
__device__ __forceinline__ float silu_f(float t){
  return t * __builtin_amdgcn_rcpf(1.f + __expf(-t));
}

// Truncation split of two fp32 into packed bf16 hi-pair and bf16 lo-pair,
// using v_perm_b32 for the 16-bit packing (1 instr per pack).
// hi+lo captures 17 mantissa bits (error <= 2^-17 |x|).
__device__ __forceinline__ void split2(float x0, float x1, unsigned &hi, unsigned &lo){
  union { float f; unsigned u; } a0, a1, m0, m1, r0, r1;
  a0.f = x0; a1.f = x1;
  m0.u = a0.u & 0xffff0000u;
  m1.u = a1.u & 0xffff0000u;
  r0.f = x0 - m0.f;
  r1.f = x1 - m1.f;
  hi = __builtin_amdgcn_perm(a1.u, a0.u, 0x07060302u);  // {a1.hi16, a0.hi16}
  lo = __builtin_amdgcn_perm(r1.u, r0.u, 0x07060302u);  // {r1.hi16, r0.hi16}
}

// Fragment-major weight prep: frag[((kk*T + tile)*64 + lane)*8 + e]
//   = W[tile*16 + (lane&15)][kk*32 + (lane>>4)*8 + e]   (0 outside valid range)
__global__ void prep_w(const float* __restrict__ wie, const float* __restrict__ wec,
                       const float* __restrict__ wbi, const float* __restrict__ wbo,
                       const float* __restrict__ wdc, const float* __restrict__ wor,
                       unsigned short* pieh, unsigned short* piel,
                       unsigned short* pech, unsigned short* pecl,
                       unsigned short* pbih, unsigned short* pbil,
                       unsigned short* pboh, unsigned short* pbol,
                       unsigned short* pdch, unsigned short* pdcl,
                       unsigned short* porh, unsigned short* porl)
{
  int t = blockIdx.x*256 + threadIdx.x;   // 0..16383
  int e = t & 7, l = (t >> 3) & 63, rem = t >> 9;
  int r16 = l & 15;
  int kq = (l >> 4)*8 + e;                // k within one 32-block
  #define WSPLIT(val, H, L) { float w_=(val); unsigned short h_=f2bf(w_); H[t]=h_; L[t]=f2bf(w_-bf2f(h_)); }
  if (t < 4096){                          // KK=1, T=8 (ie: K=3 pad, bo: K=16 pad)
    int tile = rem & 7; int row = tile*16 + r16; int k = kq;
    WSPLIT((k < 3) ? wie[row*3 + k] : 0.f, pieh, piel);
    WSPLIT((k < 16) ? wbo[row*16 + k] : 0.f, pboh, pbol);
  }
  if (t < 16384){                         // KK=4, T=8 (ec, dc)
    int kk = rem >> 3, tile = rem & 7; int row = tile*16 + r16; int k = kk*32 + kq;
    WSPLIT(wec[row*128 + k], pech, pecl);
    WSPLIT(wdc[row*128 + k], pdch, pdcl);
  }
  if (t < 2048){                          // KK=4, T=1 (bi: 16 rows; or: 3 rows pad)
    int kk = rem; int row = r16; int k = kk*32 + kq;
    WSPLIT(wbi[row*128 + k], pbih, pbil);
    WSPLIT((row < 3) ? wor[row*128 + k] : 0.f, porh, porl);
  }
  #undef WSPLIT
}

// Exact input-side outputs: out0 = jPxPyPzE, out2 = j_rot (copy)
__global__ void k_out02(const float* __restrict__ jin, float* __restrict__ out0,
                        float* __restrict__ out2)
{
  int b = blockIdx.x*256 + threadIdx.x;
  if (b >= NJETS) return;
  #pragma unroll
  for (int p=0;p<4;p++){
    float ptv = jin[b*16+p], ev = jin[b*16+4+p], ph = jin[b*16+8+p], mv = jin[b*16+12+p];
    out0[(size_t)b*16 + p]      = ptv*cosf(ph);
    out0[(size_t)b*16 + 4 + p]  = ptv*sinf(ph);
    out0[(size_t)b*16 + 8 + p]  = ptv*sinhf(ev);
    float tt = ptv*coshf(ev);
    out0[(size_t)b*16 + 12 + p] = sqrtf(tt*tt + mv*mv);
  }
  #pragma unroll
  for (int i=0;i<16;i+=4)
    *(float4*)(out2 + (size_t)b*16 + i) = *(const float4*)(jin + (size_t)b*16 + i);
}

// Fused conv kernel, one chunk of whole GBN groups. M=256 rows/block, 8 waves,
// 2 row-stripes/wave (stripe1 = +128). BOTH hi and lo weights staged in LDS
// fragment-major -> inner loop is pure ds_read_b128 + MFMA (no global deps).
// Epilogue for OTILES==8 stages packed fp16 rows in per-wave LDS tiles (aliasing
// the weight region after a barrier), then stores 1KB fully-coalesced.
// Preamble (PREVC>0): per-block reduce of previous layer's partials -> alpha/beta in LDS.
// SRC: 0 = jp from j; 1 = fp16 y[128] + affsilu; 3 = fp32 y3[16] + affsilu + z write.
// OTILES==8 -> fp16 output; OTILES==1 -> fp32 output (16-ch).
template<int OTILES, int KK, int SRC, int AUXOUT, int AUXIN, int PREVC>
__global__ __launch_bounds__(512, 4)
void conv_k(const float* __restrict__ jin, int rowbase,
            const void* __restrict__ yin,
            const float* __restrict__ partIn,
            const float* __restrict__ prevGain, const float* __restrict__ prevBias,
            int prevCvalid,
            const unsigned short* __restrict__ whM, const unsigned short* __restrict__ wlM,
            const unsigned short* __restrict__ whA, const unsigned short* __restrict__ wlA,
            const float* __restrict__ bias, int cvalid,
            void* __restrict__ yout, float* __restrict__ youtaux,
            const float* __restrict__ yinaux,
            float* __restrict__ partOut, float* __restrict__ zout)
{
  constexpr int COUT = OTILES*16;
  constexpr int WCNT   = KK*OTILES*512;                  // elems per weight matrix
  constexpr int WBYTES = WCNT*2*2;                       // hi+lo bytes
  constexpr int STBYTES = (OTILES==8) ? 8*16*68*4 : 0;   // 8 waves x [16][68] dwords
  constexpr int UBYTES  = (WBYTES > STBYTES) ? WBYTES : STBYTES;
  const int tid = threadIdx.x;
  const int wv = tid >> 6, lane = tid & 63, r16 = lane & 15, g4 = lane >> 4;
  const int blk = blockIdx.x;
  const int row0 = blk*256 + wv*16;     // stripe0 rows (chunk-local); stripe1 = +128
  const int grp = blk >> 4;             // 16 blocks per GBN group

  __shared__ __align__(16) char ldsU[UBYTES];            // weights hi|lo  /  store-staging
  unsigned short* ldsWh = (unsigned short*)ldsU;
  unsigned short* ldsWl = (unsigned short*)(ldsU) + WCNT;
  __shared__ __align__(16) unsigned short ldsWhA[AUXOUT ? KK*512 : 8];
  __shared__ float sAB[256];
  __shared__ float sc[8][OTILES][16][2];

  // ---- preamble: compute this group's alpha/beta from partIn ----
  if (PREVC > 0){
    constexpr int NENT = PREVC*2;
    if (tid < NENT){
      float s = 0.f;
      const float* p = partIn + (size_t)(grp*16)*256 + tid;
      #pragma unroll
      for (int i=0;i<16;i++) s += p[(size_t)i*256];
      float other = __shfl_xor(s, 1);
      if ((tid & 1) == 0){
        int c = tid >> 1;
        float mean = s * (1.f/4096.f);
        float var  = other * (1.f/4096.f) - mean*mean;
        float a = 0.f, b = 0.f;
        if (c < prevCvalid){
          a = prevGain[c] * rsqrtf(var + 1e-5f);
          b = prevBias[c] - mean*a;
        }
        sAB[c] = a; sAB[128 + c] = b;
      }
    }
  }
  { // stage hi+lo weights into LDS (fragment-major is linear -> coalesced)
    const float4* gh = (const float4*)whM;
    const float4* gl = (const float4*)wlM;
    float4* lh = (float4*)ldsWh;
    float4* ll = (float4*)ldsWl;
    for (int i = tid; i < WCNT/8; i += 512){ lh[i] = gh[i]; ll[i] = gl[i]; }
    if (AUXOUT){
      const float4* ga = (const float4*)whA;
      float4* la = (float4*)ldsWhA;
      for (int i = tid; i < KK*64; i += 512) la[i] = ga[i];
    }
  }
  __syncthreads();

  f32x4 acc[2][OTILES];
  f32x4 accA[2];
  #pragma unroll
  for (int s=0;s<2;s++){
    #pragma unroll
    for (int t=0;t<OTILES;t++){
      int c = t*16 + r16;
      float bv = (c < cvalid) ? bias[c] : 0.f;
      if (AUXIN){
        #pragma unroll
        for (int jj=0;jj<4;jj++)
          acc[s][t][jj] = bv + yinaux[(size_t)(row0 + s*128 + g4*4 + jj)*16 + r16];
      } else {
        acc[s][t][0]=bv; acc[s][t][1]=bv; acc[s][t][2]=bv; acc[s][t][3]=bv;
      }
    }
    if (AUXOUT){ accA[s][0]=0.f; accA[s][1]=0.f; accA[s][2]=0.f; accA[s][3]=0.f; }
  }

  auto loadA = [&](int kk, int s, float* xs){
    const int rowL = row0 + s*128 + r16;
    if (SRC == 1){
      const unsigned short* yb = (const unsigned short*)yin;
      union { uint4 u; unsigned short us[8]; } raw;
      raw.u = *(const uint4*)(yb + (size_t)rowL*128 + kk*32 + g4*8);
      #pragma unroll
      for (int e=0;e<8;e++) xs[e] = __half2float(__ushort_as_half(raw.us[e]));
    } else if (SRC == 3){
      const float* yf = (const float*)yin;
      if (g4 < 2){
        *(float4*)&xs[0] = *(const float4*)(yf + (size_t)rowL*16 + g4*8);
        *(float4*)&xs[4] = *(const float4*)(yf + (size_t)rowL*16 + g4*8 + 4);
      } else {
        #pragma unroll
        for (int e=0;e<8;e++) xs[e] = 0.f;
      }
    } else { // SRC == 0
      #pragma unroll
      for (int e=0;e<8;e++) xs[e] = 0.f;
      if (g4 == 0){
        int rowG = rowbase + rowL; int b = rowG >> 2, p = rowG & 3;
        xs[0] = jin[b*16 + p];
        xs[1] = jin[b*16 + 4 + p];
        xs[2] = jin[b*16 + 8 + p];
      }
    }
  };

  float cur[2][8], nxt[2][8];
  loadA(0, 0, cur[0]); loadA(0, 1, cur[1]);

  #pragma unroll
  for (int kk=0; kk<KK; kk++){
    if (kk+1 < KK){ loadA(kk+1, 0, nxt[0]); loadA(kk+1, 1, nxt[1]); }

    float alf[8], bef[8];
    if (SRC != 0){
      const int kb = (SRC==1) ? (kk*32 + g4*8) : (g4 < 2 ? g4*8 : 0);
      #pragma unroll
      for (int e=0;e<8;e++){ alf[e] = sAB[kb+e]; bef[e] = sAB[128+kb+e]; }
    }

    short8 ah[2], al[2];
    #pragma unroll
    for (int s=0;s<2;s++){
      float xs[8];
      if (SRC == 0){
        #pragma unroll
        for (int e=0;e<8;e++) xs[e] = cur[s][e];
        if (g4 == 0) xs[0] = log1pf(cur[s][0]);
      } else if (SRC == 1){
        #pragma unroll
        for (int e=0;e<8;e++) xs[e] = silu_f(fmaf(cur[s][e], alf[e], bef[e]));
      } else { // SRC == 3
        if (g4 < 2){
          const int kb = g4*8;
          const int rowG = rowbase + row0 + s*128 + r16;
          const int b = rowG >> 2, p = rowG & 3;
          #pragma unroll
          for (int e=0;e<8;e++){
            float sv = silu_f(fmaf(cur[s][e], alf[e], bef[e]));
            zout[(size_t)b*64 + (size_t)(kb+e)*4 + p] = sv;   // z (B,16,4)
            xs[e] = sv;
          }
        } else {
          #pragma unroll
          for (int e=0;e<8;e++) xs[e] = 0.f;
        }
      }
      union { uint4 u; short8 v; } AH, AL;
      #pragma unroll
      for (int e=0;e<8;e+=2){
        unsigned hi, lo;
        split2(xs[e], xs[e+1], hi, lo);
        ((unsigned*)&AH)[e>>1] = hi;
        ((unsigned*)&AL)[e>>1] = lo;
      }
      ah[s] = AH.v; al[s] = AL.v;
    }

    #pragma unroll
    for (int t=0;t<OTILES;t++){
      const int off = ((kk*OTILES + t)*64 + lane)*8;
      short8 Bh = *(const short8*)(ldsWh + off);
      short8 Bl = *(const short8*)(ldsWl + off);
      #pragma unroll
      for (int s=0;s<2;s++){
        acc[s][t] = __builtin_amdgcn_mfma_f32_16x16x32_bf16(ah[s], Bh, acc[s][t], 0,0,0);
        acc[s][t] = __builtin_amdgcn_mfma_f32_16x16x32_bf16(al[s], Bh, acc[s][t], 0,0,0);
        acc[s][t] = __builtin_amdgcn_mfma_f32_16x16x32_bf16(ah[s], Bl, acc[s][t], 0,0,0);
      }
    }
    if (AUXOUT){
      const int off = (kk*64 + lane)*8;
      short8 Bh = *(const short8*)(ldsWhA + off);
      union { uint4 u; short8 v; } Bl; Bl.u = *(const uint4*)(wlA + off);
      #pragma unroll
      for (int s=0;s<2;s++){
        accA[s] = __builtin_amdgcn_mfma_f32_16x16x32_bf16(ah[s], Bh,   accA[s], 0,0,0);
        accA[s] = __builtin_amdgcn_mfma_f32_16x16x32_bf16(al[s], Bh,   accA[s], 0,0,0);
        accA[s] = __builtin_amdgcn_mfma_f32_16x16x32_bf16(ah[s], Bl.v, accA[s], 0,0,0);
      }
    }

    #pragma unroll
    for (int s=0;s<2;s++)
      #pragma unroll
      for (int e=0;e<8;e++) cur[s][e] = nxt[s][e];
  }

  // ---- epilogue part 1: per-channel sums (+ direct store for 16-ch fp32 out) ----
  #pragma unroll
  for (int t=0;t<OTILES;t++){
    float ss1 = 0.f, ss2 = 0.f;
    const int c = t*16 + r16;
    #pragma unroll
    for (int s=0;s<2;s++){
      #pragma unroll
      for (int jj=0;jj<4;jj++){
        float v = acc[s][t][jj];
        if (OTILES == 1)
          ((float*)yout)[(size_t)(row0 + s*128 + g4*4 + jj)*16 + c] = v;
        ss1 += v; ss2 += v*v;
      }
    }
    ss1 += __shfl_xor(ss1, 16); ss1 += __shfl_xor(ss1, 32);
    ss2 += __shfl_xor(ss2, 16); ss2 += __shfl_xor(ss2, 32);
    if (g4 == 0){ sc[wv][t][r16][0] = ss1; sc[wv][t][r16][1] = ss2; }
  }
  if (AUXOUT){
    #pragma unroll
    for (int s=0;s<2;s++)
      #pragma unroll
      for (int jj=0;jj<4;jj++)
        youtaux[(size_t)(row0 + s*128 + g4*4 + jj)*16 + r16] = accA[s][jj];
  }
  __syncthreads();   // all waves done with weight LDS (staging aliases it); sc filled

  // ---- epilogue part 2: fp16 y store via per-wave LDS transpose (1KB/instr) ----
  if (OTILES == 8){
    unsigned* stg = (unsigned*)ldsU + wv*(16*68);
    #pragma unroll
    for (int s=0;s<2;s++){
      #pragma unroll
      for (int t=0;t<8;t++){
        #pragma unroll
        for (int jj=0;jj<4;jj++){
          unsigned u = (unsigned)__half_as_ushort(__float2half_rn(acc[s][t][jj]));
          unsigned partner = __shfl_xor((int)u, 1);
          if ((r16 & 1) == 0)
            stg[(g4*4+jj)*68 + t*8 + (r16>>1)] = u | (partner << 16);
        }
      }
      #pragma unroll
      for (int i=0;i<4;i++){
        const int r = i*4 + g4;
        const int d0 = r16*4;
        uint4 val = *(const uint4*)(stg + r*68 + d0);
        *(uint4*)((unsigned*)yout + (size_t)(row0 + s*128 + r)*64 + d0) = val;
      }
    }
  }
  if (tid < COUT*2){
    int c = tid >> 1, sbit = tid & 1;
    float p = 0.f;
    #pragma unroll
    for (int w=0;w<8;w++) p += sc[w][c>>4][c&15][sbit];
    partOut[(size_t)blk*256 + tid] = p;
  }
}

// Output-side: compute ab6 from L6 partials, then affsilu(y6) -> out3 / out1.
__global__ void k_out13(const float* __restrict__ y6, const float* __restrict__ partIn,
                        const float* __restrict__ gor, const float* __restrict__ beor,
                        int jetbase, int njets_chunk,
                        float* __restrict__ out1, float* __restrict__ out3)
{
  __shared__ float sA[3], sB[3];
  int g = blockIdx.x >> 2;                 // 4 blocks (256 jets) per group
  if (threadIdx.x < 6){
    int tidp = threadIdx.x;
    float s = 0.f;
    const float* p = partIn + (size_t)(g*16)*256 + tidp;
    #pragma unroll
    for (int i=0;i<16;i++) s += p[(size_t)i*256];
    float other = __shfl_xor(s, 1);
    if ((tidp & 1) == 0){
      int c = tidp >> 1;
      float mean = s * (1.f/4096.f);
      float var  = other * (1.f/4096.f) - mean*mean;
      float a = gor[c] * rsqrtf(var + 1e-5f);
      sA[c] = a; sB[c] = beor[c] - mean*a;
    }
  }
  __syncthreads();
  int jl = blockIdx.x*256 + threadIdx.x;
  if (jl >= njets_chunk) return;
  int b = jetbase + jl;
  float a0 = sA[0], a1 = sA[1], a2 = sA[2];
  float b0 = sB[0], b1 = sB[1], b2 = sB[2];
  #pragma unroll
  for (int p=0;p<4;p++){
    size_t row = (size_t)jl*4 + p;
    float x0 = silu_f(fmaf(y6[row*16+0], a0, b0));
    float x1 = silu_f(fmaf(y6[row*16+1], a1, b1));
    float x2 = silu_f(fmaf(y6[row*16+2], a2, b2));
    float rPt = coshf(x0) + 39.f;
    out3[(size_t)b*12 + p]     = rPt;
    out3[(size_t)b*12 + 4 + p] = x1;
    out3[(size_t)b*12 + 8 + p] = x2;
    float rPz = rPt * sinhf(x1);
    out1[(size_t)b*16 + p]      = rPt * cosf(x2);
    out1[(size_t)b*16 + 4 + p]  = rPt * sinf(x2);
    out1[(size_t)b*16 + 8 + p]  = rPz;
    out1[(size_t)b*16 + 12 + p] = sqrtf(rPt*rPt + rPz*rPz);
  }
}

extern "C" void kernel_launch(void* const* d_in, const int* in_sizes, int n_in,
                              void* d_out, int out_size, void* d_ws, size_t ws_size,
                              hipStream_t stream)
{
  const float* j    = (const float*)d_in[0];
  const float* w_ie = (const float*)d_in[1];
  const float* b_ie = (const float*)d_in[2];
  const float* g_ie = (const float*)d_in[3];
  const float* be_ie= (const float*)d_in[4];
  const float* w_ec = (const float*)d_in[5];
  const float* b_ec = (const float*)d_in[6];
  const float* g_ec = (const float*)d_in[7];
  const float* be_ec= (const float*)d_in[8];
  const float* w_bi = (const float*)d_in[9];
  const float* b_bi = (const float*)d_in[10];
  const float* g_bi = (const float*)d_in[11];
  const float* be_bi= (const float*)d_in[12];
  const float* w_bo = (const float*)d_in[13];
  const float* b_bo = (const float*)d_in[14];
  const float* g_bo = (const float*)d_in[15];
  const float* be_bo= (const float*)d_in[16];
  const float* w_dc = (const float*)d_in[17];
  const float* b_dc = (const float*)d_in[18];
  const float* w_or = (const float*)d_in[19];
  const float* b_or = (const float*)d_in[20];
  const float* g_or = (const float*)d_in[21];
  const float* be_or= (const float*)d_in[22];

  float* out  = (float*)d_out;
  float* out0 = out;
  float* out1 = out + 1048576;
  float* out2 = out + 2097152;
  float* out3 = out + 3145728;
  float* out4 = out + 3932160;   // z (B,16,4)

  char* ws = (char*)d_ws;
  unsigned short* pieh = (unsigned short*)(ws);
  unsigned short* piel = pieh + 4096;
  unsigned short* pech = piel + 4096;
  unsigned short* pecl = pech + 16384;
  unsigned short* pbih = pecl + 16384;
  unsigned short* pbil = pbih + 2048;
  unsigned short* pboh = pbil + 2048;
  unsigned short* pbol = pboh + 4096;
  unsigned short* pdch = pbol + 4096;
  unsigned short* pdcl = pdch + 16384;
  unsigned short* porh = pdcl + 16384;
  unsigned short* porl = porh + 2048;

  // Chunking: G whole GBN groups (1024 jets = 4096 rows) per chunk.
  // perG = yA + yB (fp16 [4096][128]) + y3 (fp32 [4096][16]) + 2 part bufs
  const size_t fixedB = 196608;
  const size_t perG   = 2424832;   // superset of 2*1048576 + 262144 + 2*16384
  int G = 64;
  while (G > 1 && fixedB + (size_t)G*perG > ws_size) G >>= 1;

  unsigned short* yA = (unsigned short*)(ws + fixedB);   // fp16 [G*4096][128]
  unsigned short* yB = yA + (size_t)G*4096*128;          // fp16 [G*4096][128]
  float* y3    = (float*)(yB + (size_t)G*4096*128);      // fp32 [G*4096][16]
  float* partA = y3 + (size_t)G*4096*16;                 // [G*16][256]
  float* partB = partA + (size_t)G*16*256;               // [G*16][256]

  prep_w<<<64,256,0,stream>>>(w_ie,w_ec,w_bi,w_bo,w_dc,w_or,
                              pieh,piel,pech,pecl,pbih,pbil,pboh,pbol,pdch,pdcl,porh,porl);
  k_out02<<<256,256,0,stream>>>(j, out0, out2);

  for (int g0 = 0; g0 < 64; g0 += G){
    const int R0 = g0*4096;
    const int JB = g0*1024;
    const int NB = G*16;             // blocks per conv (256 rows each)
    // L1: jp -> y1 (yA fp16); partials -> partA
    conv_k<8,1,0,0,0,0><<<NB,512,0,stream>>>(j, R0, nullptr,
        nullptr, nullptr, nullptr, 0,
        pieh, piel, nullptr, nullptr,
        b_ie, 128, yA, nullptr, nullptr, partA, nullptr);
    // L2: ab1 from partA (g_ie); y2 = Wec x1 (yB); y3a = Wbi x1 (y3); partials -> partB
    conv_k<8,4,1,1,0,128><<<NB,512,0,stream>>>(nullptr, R0, yA,
        partA, g_ie, be_ie, 128,
        pech, pecl, pbih, pbil,
        b_ec, 128, yB, y3, nullptr, partB, nullptr);
    // L3: ab2 from partB (g_ec); y3 = y3a + Wbi affsilu2(y2); partials -> partA
    conv_k<1,4,1,0,1,128><<<NB,512,0,stream>>>(nullptr, R0, yB,
        partB, g_ec, be_ec, 128,
        pbih, pbil, nullptr, nullptr,
        b_bi, 16, y3, nullptr, y3, partA, nullptr);
    // L4: ab3 from partA (g_bi); z = affsilu3(y3) -> out4; y4 = Wbo z (yA); partials -> partB
    conv_k<8,1,3,0,0,16><<<NB,512,0,stream>>>(nullptr, R0, y3,
        partA, g_bi, be_bi, 16,
        pboh, pbol, nullptr, nullptr,
        b_bo, 128, yA, nullptr, nullptr, partB, out4);
    // L5: ab4 from partB (g_bo); y5 = Wdc x4 (yB); y6a = Wor x4 (y3); partials -> partA
    conv_k<8,4,1,1,0,128><<<NB,512,0,stream>>>(nullptr, R0, yA,
        partB, g_bo, be_bo, 128,
        pdch, pdcl, porh, porl,
        b_dc, 128, yB, y3, nullptr, partA, nullptr);
    // L6: ab5 from partA (g_ec — reference reuses g_ec/be_ec); y6 = y6a + Wor affsilu5(y5); partials -> partB
    conv_k<1,4,1,0,1,128><<<NB,512,0,stream>>>(nullptr, R0, yB,
        partA, g_ec, be_ec, 128,
        porh, porl, nullptr, nullptr,
        b_or, 3, y3, nullptr, y3, partB, nullptr);
    // outputs 1 and 3 (ab6 from partB, g_or)
    k_out13<<<G*4,256,0,stream>>>(y3, partB, g_or, be_or, JB, G*1024, out1, out3);
  }
}

// Round 10
// 234.186 us; speedup vs baseline: 3.5119x; 1.0482x over previous
//
#include <hip/hip_runtime.h>
#include <hip/hip_fp16.h>
#include <math.h>

#define NJETS 65536

typedef __attribute__((ext_vector_type(8))) short short8;
typedef __attribute__((ext_vector_type(4))) float f32x4;

__device__ __forceinline__ float bf2f(unsigned short u){
  union { unsigned int i; float f; } v; v.i = ((unsigned int)u) << 16; return v.f;
}
__device__ __forceinline__ unsigned short f2bf(float f){
  union { float ff; unsigned int i; } v; v.ff = f;
  unsigned int r = (v.i + 0x7fffu + ((v.i >> 16) & 1u)) >> 16;   // RTNE
  return (unsigned short)r;
}
__device__ __forceinline__ float silu_f(float t){
  return t * __builtin_amdgcn_rcpf(1.f + __expf(-t));
}

// Truncation split of two fp32 into packed bf16 hi-pair and bf16 lo-pair,
// using v_perm_b32 for the 16-bit packing (1 instr per pack).
// hi+lo captures 17 mantissa bits (error <= 2^-17 |x|).
__device__ __forceinline__ void split2(float x0, float x1, unsigned &hi, unsigned &lo){
  union { float f; unsigned u; } a0, a1, m0, m1, r0, r1;
  a0.f = x0; a1.f = x1;
  m0.u = a0.u & 0xffff0000u;
  m1.u = a1.u & 0xffff0000u;
  r0.f = x0 - m0.f;
  r1.f = x1 - m1.f;
  hi = __builtin_amdgcn_perm(a1.u, a0.u, 0x07060302u);  // {a1.hi16, a0.hi16}
  lo = __builtin_amdgcn_perm(r1.u, r0.u, 0x07060302u);  // {r1.hi16, r0.hi16}
}

// Fragment-major weight prep: frag[((kk*T + tile)*64 + lane)*8 + e]
//   = W[tile*16 + (lane&15)][kk*32 + (lane>>4)*8 + e]   (0 outside valid range)
__global__ void prep_w(const float* __restrict__ wie, const float* __restrict__ wec,
                       const float* __restrict__ wbi, const float* __restrict__ wbo,
                       const float* __restrict__ wdc, const float* __restrict__ wor,
                       unsigned short* pieh, unsigned short* piel,
                       unsigned short* pech, unsigned short* pecl,
                       unsigned short* pbih, unsigned short* pbil,
                       unsigned short* pboh, unsigned short* pbol,
                       unsigned short* pdch, unsigned short* pdcl,
                       unsigned short* porh, unsigned short* porl)
{
  int t = blockIdx.x*256 + threadIdx.x;   // 0..16383
  int e = t & 7, l = (t >> 3) & 63, rem = t >> 9;
  int r16 = l & 15;
  int kq = (l >> 4)*8 + e;                // k within one 32-block
  #define WSPLIT(val, H, L) { float w_=(val); unsigned short h_=f2bf(w_); H[t]=h_; L[t]=f2bf(w_-bf2f(h_)); }
  if (t < 4096){                          // KK=1, T=8 (ie: K=3 pad, bo: K=16 pad)
    int tile = rem & 7; int row = tile*16 + r16; int k = kq;
    WSPLIT((k < 3) ? wie[row*3 + k] : 0.f, pieh, piel);
    WSPLIT((k < 16) ? wbo[row*16 + k] : 0.f, pboh, pbol);
  }
  if (t < 16384){                         // KK=4, T=8 (ec, dc)
    int kk = rem >> 3, tile = rem & 7; int row = tile*16 + r16; int k = kk*32 + kq;
    WSPLIT(wec[row*128 + k], pech, pecl);
    WSPLIT(wdc[row*128 + k], pdch, pdcl);
  }
  if (t < 2048){                          // KK=4, T=1 (bi: 16 rows; or: 3 rows pad)
    int kk = rem; int row = r16; int k = kk*32 + kq;
    WSPLIT(wbi[row*128 + k], pbih, pbil);
    WSPLIT((row < 3) ? wor[row*128 + k] : 0.f, porh, porl);
  }
  #undef WSPLIT
}

// Exact input-side outputs: out0 = jPxPyPzE, out2 = j_rot (copy)
__global__ void k_out02(const float* __restrict__ jin, float* __restrict__ out0,
                        float* __restrict__ out2)
{
  int b = blockIdx.x*256 + threadIdx.x;
  if (b >= NJETS) return;
  #pragma unroll
  for (int p=0;p<4;p++){
    float ptv = jin[b*16+p], ev = jin[b*16+4+p], ph = jin[b*16+8+p], mv = jin[b*16+12+p];
    out0[(size_t)b*16 + p]      = ptv*cosf(ph);
    out0[(size_t)b*16 + 4 + p]  = ptv*sinf(ph);
    out0[(size_t)b*16 + 8 + p]  = ptv*sinhf(ev);
    float tt = ptv*coshf(ev);
    out0[(size_t)b*16 + 12 + p] = sqrtf(tt*tt + mv*mv);
  }
  #pragma unroll
  for (int i=0;i<16;i+=4)
    *(float4*)(out2 + (size_t)b*16 + i) = *(const float4*)(jin + (size_t)b*16 + i);
}

// Fused conv kernel, one chunk of whole GBN groups. M=256 rows/block, 8 waves,
// 2 row-stripes/wave (stripe1 = +128). Hi-weights staged in LDS fragment-major;
// lo-weights streamed from L2 (round-7 proven scheme).
// ALL global writes are full-line: fp16 y via per-wave LDS transpose (1KB/instr);
// fp32 16-ch outputs (aux y3a/y6a, OTILES==1 y3/y6, z) staged per-wave in LDS
// and stored as one uint4/lane (1KB aligned) per stripe.
// Preamble (PREVC>0): per-block reduce of previous layer's partials -> alpha/beta in LDS.
// SRC: 0 = jp from j; 1 = fp16 y[128] + affsilu; 3 = fp32 y3[16] + affsilu + z write.
template<int OTILES, int KK, int SRC, int AUXOUT, int AUXIN, int PREVC>
__global__ __launch_bounds__(512, 4)
void conv_k(const float* __restrict__ jin, int rowbase,
            const void* __restrict__ yin,
            const float* __restrict__ partIn,
            const float* __restrict__ prevGain, const float* __restrict__ prevBias,
            int prevCvalid,
            const unsigned short* __restrict__ whM, const unsigned short* __restrict__ wlM,
            const unsigned short* __restrict__ whA, const unsigned short* __restrict__ wlA,
            const float* __restrict__ bias, int cvalid,
            void* __restrict__ yout, float* __restrict__ youtaux,
            const float* __restrict__ yinaux,
            float* __restrict__ partOut, float* __restrict__ zout)
{
  constexpr int COUT = OTILES*16;
  constexpr int WCNT   = KK*OTILES*512;                  // elems per weight matrix (hi)
  constexpr int WBYTES = WCNT*2;                         // hi-only bytes
  constexpr int STBYTES = (OTILES==8) ? 8*16*68*4 : 8*256*4;  // per-wave staging region
  constexpr int UBYTES  = (WBYTES > STBYTES) ? WBYTES : STBYTES;
  const int tid = threadIdx.x;
  const int wv = tid >> 6, lane = tid & 63, r16 = lane & 15, g4 = lane >> 4;
  const int blk = blockIdx.x;
  const int row0 = blk*256 + wv*16;     // stripe0 rows (chunk-local); stripe1 = +128
  const int grp = blk >> 4;             // 16 blocks per GBN group

  __shared__ __align__(16) char ldsU[UBYTES];            // weights(hi) | store-staging
  unsigned short* ldsWh = (unsigned short*)ldsU;
  __shared__ __align__(16) unsigned short ldsWhA[AUXOUT ? KK*512 : 8];
  __shared__ __align__(16) unsigned stgZ[(SRC==3) ? 8*2*256 : 8];  // z staging (pre-barrier)
  __shared__ float sAB[256];
  __shared__ float sc[8][OTILES][16][2];

  // ---- preamble: compute this group's alpha/beta from partIn ----
  if (PREVC > 0){
    constexpr int NENT = PREVC*2;
    if (tid < NENT){
      float s = 0.f;
      const float* p = partIn + (size_t)(grp*16)*256 + tid;
      #pragma unroll
      for (int i=0;i<16;i++) s += p[(size_t)i*256];
      float other = __shfl_xor(s, 1);
      if ((tid & 1) == 0){
        int c = tid >> 1;
        float mean = s * (1.f/4096.f);
        float var  = other * (1.f/4096.f) - mean*mean;
        float a = 0.f, b = 0.f;
        if (c < prevCvalid){
          a = prevGain[c] * rsqrtf(var + 1e-5f);
          b = prevBias[c] - mean*a;
        }
        sAB[c] = a; sAB[128 + c] = b;
      }
    }
  }
  { // stage hi-weights into LDS (fragment-major is linear -> coalesced)
    const float4* gw = (const float4*)whM;
    float4* lw = (float4*)ldsU;
    for (int i = tid; i < WCNT/8; i += 512) lw[i] = gw[i];
    if (AUXOUT){
      const float4* ga = (const float4*)whA;
      float4* la = (float4*)ldsWhA;
      for (int i = tid; i < KK*64; i += 512) la[i] = ga[i];
    }
  }
  __syncthreads();

  f32x4 acc[2][OTILES];
  f32x4 accA[2];
  #pragma unroll
  for (int s=0;s<2;s++){
    #pragma unroll
    for (int t=0;t<OTILES;t++){
      int c = t*16 + r16;
      float bv = (c < cvalid) ? bias[c] : 0.f;
      if (AUXIN){
        #pragma unroll
        for (int jj=0;jj<4;jj++)
          acc[s][t][jj] = bv + yinaux[(size_t)(row0 + s*128 + g4*4 + jj)*16 + r16];
      } else {
        acc[s][t][0]=bv; acc[s][t][1]=bv; acc[s][t][2]=bv; acc[s][t][3]=bv;
      }
    }
    if (AUXOUT){ accA[s][0]=0.f; accA[s][1]=0.f; accA[s][2]=0.f; accA[s][3]=0.f; }
  }

  auto loadA = [&](int kk, int s, float* xs){
    const int rowL = row0 + s*128 + r16;
    if (SRC == 1){
      const unsigned short* yb = (const unsigned short*)yin;
      union { uint4 u; unsigned short us[8]; } raw;
      raw.u = *(const uint4*)(yb + (size_t)rowL*128 + kk*32 + g4*8);
      #pragma unroll
      for (int e=0;e<8;e++) xs[e] = __half2float(__ushort_as_half(raw.us[e]));
    } else if (SRC == 3){
      const float* yf = (const float*)yin;
      if (g4 < 2){
        *(float4*)&xs[0] = *(const float4*)(yf + (size_t)rowL*16 + g4*8);
        *(float4*)&xs[4] = *(const float4*)(yf + (size_t)rowL*16 + g4*8 + 4);
      } else {
        #pragma unroll
        for (int e=0;e<8;e++) xs[e] = 0.f;
      }
    } else { // SRC == 0
      #pragma unroll
      for (int e=0;e<8;e++) xs[e] = 0.f;
      if (g4 == 0){
        int rowG = rowbase + rowL; int b = rowG >> 2, p = rowG & 3;
        xs[0] = jin[b*16 + p];
        xs[1] = jin[b*16 + 4 + p];
        xs[2] = jin[b*16 + 8 + p];
      }
    }
  };

  float cur[2][8], nxt[2][8];
  loadA(0, 0, cur[0]); loadA(0, 1, cur[1]);

  #pragma unroll
  for (int kk=0; kk<KK; kk++){
    if (kk+1 < KK){ loadA(kk+1, 0, nxt[0]); loadA(kk+1, 1, nxt[1]); }

    float alf[8], bef[8];
    if (SRC != 0){
      const int kb = (SRC==1) ? (kk*32 + g4*8) : (g4 < 2 ? g4*8 : 0);
      #pragma unroll
      for (int e=0;e<8;e++){ alf[e] = sAB[kb+e]; bef[e] = sAB[128+kb+e]; }
    }

    short8 ah[2], al[2];
    #pragma unroll
    for (int s=0;s<2;s++){
      float xs[8];
      if (SRC == 0){
        #pragma unroll
        for (int e=0;e<8;e++) xs[e] = cur[s][e];
        if (g4 == 0) xs[0] = log1pf(cur[s][0]);
      } else if (SRC == 1){
        #pragma unroll
        for (int e=0;e<8;e++) xs[e] = silu_f(fmaf(cur[s][e], alf[e], bef[e]));
      } else { // SRC == 3 : stage z into LDS (full-line store later)
        if (g4 < 2){
          #pragma unroll
          for (int e=0;e<8;e++){
            float sv = silu_f(fmaf(cur[s][e], alf[e], bef[e]));
            union { float f; unsigned u; } cv; cv.f = sv;
            stgZ[(wv*2 + s)*256 + (r16>>2)*64 + (g4*8+e)*4 + (r16&3)] = cv.u;
            xs[e] = sv;
          }
        } else {
          #pragma unroll
          for (int e=0;e<8;e++) xs[e] = 0.f;
        }
      }
      union { uint4 u; short8 v; } AH, AL;
      #pragma unroll
      for (int e=0;e<8;e+=2){
        unsigned hi, lo;
        split2(xs[e], xs[e+1], hi, lo);
        ((unsigned*)&AH)[e>>1] = hi;
        ((unsigned*)&AL)[e>>1] = lo;
      }
      ah[s] = AH.v; al[s] = AL.v;
    }

    #pragma unroll
    for (int t=0;t<OTILES;t++){
      const int off = ((kk*OTILES + t)*64 + lane)*8;
      short8 Bh = *(const short8*)(ldsWh + off);
      union { uint4 u; short8 v; } Bl; Bl.u = *(const uint4*)(wlM + off);
      #pragma unroll
      for (int s=0;s<2;s++){
        acc[s][t] = __builtin_amdgcn_mfma_f32_16x16x32_bf16(ah[s], Bh,   acc[s][t], 0,0,0);
        acc[s][t] = __builtin_amdgcn_mfma_f32_16x16x32_bf16(al[s], Bh,   acc[s][t], 0,0,0);
        acc[s][t] = __builtin_amdgcn_mfma_f32_16x16x32_bf16(ah[s], Bl.v, acc[s][t], 0,0,0);
      }
    }
    if (AUXOUT){
      const int off = (kk*64 + lane)*8;
      short8 Bh = *(const short8*)(ldsWhA + off);
      union { uint4 u; short8 v; } Bl; Bl.u = *(const uint4*)(wlA + off);
      #pragma unroll
      for (int s=0;s<2;s++){
        accA[s] = __builtin_amdgcn_mfma_f32_16x16x32_bf16(ah[s], Bh,   accA[s], 0,0,0);
        accA[s] = __builtin_amdgcn_mfma_f32_16x16x32_bf16(al[s], Bh,   accA[s], 0,0,0);
        accA[s] = __builtin_amdgcn_mfma_f32_16x16x32_bf16(ah[s], Bl.v, accA[s], 0,0,0);
      }
    }

    #pragma unroll
    for (int s=0;s<2;s++)
      #pragma unroll
      for (int e=0;e<8;e++) cur[s][e] = nxt[s][e];
  }

  // ---- z store: per-wave private LDS -> 1KB full-line stores ----
  if (SRC == 3){
    #pragma unroll
    for (int s=0;s<2;s++){
      uint4 v = *(const uint4*)(stgZ + (wv*2 + s)*256 + lane*4);
      const int jet0 = (rowbase + row0 + s*128) >> 2;
      *(uint4*)((unsigned*)zout + (size_t)jet0*64 + lane*4) = v;
    }
  }

  // ---- epilogue part 1: per-channel sums ----
  #pragma unroll
  for (int t=0;t<OTILES;t++){
    float ss1 = 0.f, ss2 = 0.f;
    #pragma unroll
    for (int s=0;s<2;s++){
      #pragma unroll
      for (int jj=0;jj<4;jj++){
        float v = acc[s][t][jj];
        ss1 += v; ss2 += v*v;
      }
    }
    ss1 += __shfl_xor(ss1, 16); ss1 += __shfl_xor(ss1, 32);
    ss2 += __shfl_xor(ss2, 16); ss2 += __shfl_xor(ss2, 32);
    if (g4 == 0){ sc[wv][t][r16][0] = ss1; sc[wv][t][r16][1] = ss2; }
  }
  __syncthreads();   // all waves done with weight LDS (staging aliases it); sc filled

  // ---- epilogue part 2: full-line stores via per-wave LDS staging ----
  if (OTILES == 8){
    unsigned* stg = (unsigned*)ldsU + wv*(16*68);
    #pragma unroll
    for (int s=0;s<2;s++){
      #pragma unroll
      for (int t=0;t<8;t++){
        #pragma unroll
        for (int jj=0;jj<4;jj++){
          unsigned u = (unsigned)__half_as_ushort(__float2half_rn(acc[s][t][jj]));
          unsigned partner = __shfl_xor((int)u, 1);
          if ((r16 & 1) == 0)
            stg[(g4*4+jj)*68 + t*8 + (r16>>1)] = u | (partner << 16);
        }
      }
      #pragma unroll
      for (int i=0;i<4;i++){
        const int r = i*4 + g4;
        const int d0 = r16*4;
        uint4 val = *(const uint4*)(stg + r*68 + d0);
        *(uint4*)((unsigned*)yout + (size_t)(row0 + s*128 + r)*64 + d0) = val;
      }
    }
    if (AUXOUT){   // y3a/y6a: stage fp32 [16 rows][16 ch] per stripe -> 1KB store
      #pragma unroll
      for (int s=0;s<2;s++){
        #pragma unroll
        for (int jj=0;jj<4;jj++){
          union { float f; unsigned u; } cv; cv.f = accA[s][jj];
          stg[(g4*4+jj)*16 + r16] = cv.u;
        }
        uint4 v = *(const uint4*)(stg + lane*4);
        *(uint4*)((unsigned*)youtaux + (size_t)(row0 + s*128)*16 + lane*4) = v;
      }
    }
  } else {   // OTILES==1: y3/y6 fp32 [16 rows][16 ch] per stripe -> 1KB store
    unsigned* stg = (unsigned*)ldsU + wv*256;
    #pragma unroll
    for (int s=0;s<2;s++){
      #pragma unroll
      for (int jj=0;jj<4;jj++){
        union { float f; unsigned u; } cv; cv.f = acc[s][0][jj];
        stg[(g4*4+jj)*16 + r16] = cv.u;
      }
      uint4 v = *(const uint4*)(stg + lane*4);
      *(uint4*)((unsigned*)yout + (size_t)(row0 + s*128)*16 + lane*4) = v;
    }
  }
  if (tid < COUT*2){
    int c = tid >> 1, sbit = tid & 1;
    float p = 0.f;
    #pragma unroll
    for (int w=0;w<8;w++) p += sc[w][c>>4][c&15][sbit];
    partOut[(size_t)blk*256 + tid] = p;
  }
}

// Output-side: compute ab6 from L6 partials, then affsilu(y6) -> out3 / out1.
__global__ void k_out13(const float* __restrict__ y6, const float* __restrict__ partIn,
                        const float* __restrict__ gor, const float* __restrict__ beor,
                        int jetbase, int njets_chunk,
                        float* __restrict__ out1, float* __restrict__ out3)
{
  __shared__ float sA[3], sB[3];
  int g = blockIdx.x >> 2;                 // 4 blocks (256 jets) per group
  if (threadIdx.x < 6){
    int tidp = threadIdx.x;
    float s = 0.f;
    const float* p = partIn + (size_t)(g*16)*256 + tidp;
    #pragma unroll
    for (int i=0;i<16;i++) s += p[(size_t)i*256];
    float other = __shfl_xor(s, 1);
    if ((tidp & 1) == 0){
      int c = tidp >> 1;
      float mean = s * (1.f/4096.f);
      float var  = other * (1.f/4096.f) - mean*mean;
      float a = gor[c] * rsqrtf(var + 1e-5f);
      sA[c] = a; sB[c] = beor[c] - mean*a;
    }
  }
  __syncthreads();
  int jl = blockIdx.x*256 + threadIdx.x;
  if (jl >= njets_chunk) return;
  int b = jetbase + jl;
  float a0 = sA[0], a1 = sA[1], a2 = sA[2];
  float b0 = sB[0], b1 = sB[1], b2 = sB[2];
  #pragma unroll
  for (int p=0;p<4;p++){
    size_t row = (size_t)jl*4 + p;
    float x0 = silu_f(fmaf(y6[row*16+0], a0, b0));
    float x1 = silu_f(fmaf(y6[row*16+1], a1, b1));
    float x2 = silu_f(fmaf(y6[row*16+2], a2, b2));
    float rPt = coshf(x0) + 39.f;
    out3[(size_t)b*12 + p]     = rPt;
    out3[(size_t)b*12 + 4 + p] = x1;
    out3[(size_t)b*12 + 8 + p] = x2;
    float rPz = rPt * sinhf(x1);
    out1[(size_t)b*16 + p]      = rPt * cosf(x2);
    out1[(size_t)b*16 + 4 + p]  = rPt * sinf(x2);
    out1[(size_t)b*16 + 8 + p]  = rPz;
    out1[(size_t)b*16 + 12 + p] = sqrtf(rPt*rPt + rPz*rPz);
  }
}

extern "C" void kernel_launch(void* const* d_in, const int* in_sizes, int n_in,
                              void* d_out, int out_size, void* d_ws, size_t ws_size,
                              hipStream_t stream)
{
  const float* j    = (const float*)d_in[0];
  const float* w_ie = (const float*)d_in[1];
  const float* b_ie = (const float*)d_in[2];
  const float* g_ie = (const float*)d_in[3];
  const float* be_ie= (const float*)d_in[4];
  const float* w_ec = (const float*)d_in[5];
  const float* b_ec = (const float*)d_in[6];
  const float* g_ec = (const float*)d_in[7];
  const float* be_ec= (const float*)d_in[8];
  const float* w_bi = (const float*)d_in[9];
  const float* b_bi = (const float*)d_in[10];
  const float* g_bi = (const float*)d_in[11];
  const float* be_bi= (const float*)d_in[12];
  const float* w_bo = (const float*)d_in[13];
  const float* b_bo = (const float*)d_in[14];
  const float* g_bo = (const float*)d_in[15];
  const float* be_bo= (const float*)d_in[16];
  const float* w_dc = (const float*)d_in[17];
  const float* b_dc = (const float*)d_in[18];
  const float* w_or = (const float*)d_in[19];
  const float* b_or = (const float*)d_in[20];
  const float* g_or = (const float*)d_in[21];
  const float* be_or= (const float*)d_in[22];

  float* out  = (float*)d_out;
  float* out0 = out;
  float* out1 = out + 1048576;
  float* out2 = out + 2097152;
  float* out3 = out + 3145728;
  float* out4 = out + 3932160;   // z (B,16,4)

  char* ws = (char*)d_ws;
  unsigned short* pieh = (unsigned short*)(ws);
  unsigned short* piel = pieh + 4096;
  unsigned short* pech = piel + 4096;
  unsigned short* pecl = pech + 16384;
  unsigned short* pbih = pecl + 16384;
  unsigned short* pbil = pbih + 2048;
  unsigned short* pboh = pbil + 2048;
  unsigned short* pbol = pboh + 4096;
  unsigned short* pdch = pbol + 4096;
  unsigned short* pdcl = pdch + 16384;
  unsigned short* porh = pdcl + 16384;
  unsigned short* porl = porh + 2048;

  // Chunking: G whole GBN groups (1024 jets = 4096 rows) per chunk.
  // perG = yA + yB (fp16 [4096][128]) + y3 (fp32 [4096][16]) + 2 part bufs
  const size_t fixedB = 196608;
  const size_t perG   = 2424832;   // superset of 2*1048576 + 262144 + 2*16384
  int G = 64;
  while (G > 1 && fixedB + (size_t)G*perG > ws_size) G >>= 1;

  unsigned short* yA = (unsigned short*)(ws + fixedB);   // fp16 [G*4096][128]
  unsigned short* yB = yA + (size_t)G*4096*128;          // fp16 [G*4096][128]
  float* y3    = (float*)(yB + (size_t)G*4096*128);      // fp32 [G*4096][16]
  float* partA = y3 + (size_t)G*4096*16;                 // [G*16][256]
  float* partB = partA + (size_t)G*16*256;               // [G*16][256]

  prep_w<<<64,256,0,stream>>>(w_ie,w_ec,w_bi,w_bo,w_dc,w_or,
                              pieh,piel,pech,pecl,pbih,pbil,pboh,pbol,pdch,pdcl,porh,porl);
  k_out02<<<256,256,0,stream>>>(j, out0, out2);

  for (int g0 = 0; g0 < 64; g0 += G){
    const int R0 = g0*4096;
    const int JB = g0*1024;
    const int NB = G*16;             // blocks per conv (256 rows each)
    // L1: jp -> y1 (yA fp16); partials -> partA
    conv_k<8,1,0,0,0,0><<<NB,512,0,stream>>>(j, R0, nullptr,
        nullptr, nullptr, nullptr, 0,
        pieh, piel, nullptr, nullptr,
        b_ie, 128, yA, nullptr, nullptr, partA, nullptr);
    // L2: ab1 from partA (g_ie); y2 = Wec x1 (yB); y3a = Wbi x1 (y3); partials -> partB
    conv_k<8,4,1,1,0,128><<<NB,512,0,stream>>>(nullptr, R0, yA,
        partA, g_ie, be_ie, 128,
        pech, pecl, pbih, pbil,
        b_ec, 128, yB, y3, nullptr, partB, nullptr);
    // L3: ab2 from partB (g_ec); y3 = y3a + Wbi affsilu2(y2); partials -> partA
    conv_k<1,4,1,0,1,128><<<NB,512,0,stream>>>(nullptr, R0, yB,
        partB, g_ec, be_ec, 128,
        pbih, pbil, nullptr, nullptr,
        b_bi, 16, y3, nullptr, y3, partA, nullptr);
    // L4: ab3 from partA (g_bi); z = affsilu3(y3) -> out4; y4 = Wbo z (yA); partials -> partB
    conv_k<8,1,3,0,0,16><<<NB,512,0,stream>>>(nullptr, R0, y3,
        partA, g_bi, be_bi, 16,
        pboh, pbol, nullptr, nullptr,
        b_bo, 128, yA, nullptr, nullptr, partB, out4);
    // L5: ab4 from partB (g_bo); y5 = Wdc x4 (yB); y6a = Wor x4 (y3); partials -> partA
    conv_k<8,4,1,1,0,128><<<NB,512,0,stream>>>(nullptr, R0, yA,
        partB, g_bo, be_bo, 128,
        pdch, pdcl, porh, porl,
        b_dc, 128, yB, y3, nullptr, partA, nullptr);
    // L6: ab5 from partA (g_ec — reference reuses g_ec/be_ec); y6 = y6a + Wor affsilu5(y5); partials -> partB
    conv_k<1,4,1,0,1,128><<<NB,512,0,stream>>>(nullptr, R0, yB,
        partA, g_ec, be_ec, 128,
        porh, porl, nullptr, nullptr,
        b_or, 3, y3, nullptr, y3, partB, nullptr);
    // outputs 1 and 3 (ab6 from partB, g_or)
    k_out13<<<G*4,256,0,stream>>>(y3, partB, g_or, be_or, JB, G*1024, out1, out3);
  }
}